// Round 1
// baseline (202.718 us; speedup 1.0000x reference)
//
#include <hip/hip_runtime.h>
#include <hip/hip_bf16.h>
#include <math.h>

#define BB 64
#define SS 4096
#define EE 128
#define NENT 600
#define NOUT 512

// ---------------------------------------------------------------------------
// Kernel 1: scores[b,s] = dot(doc_emb[b,s,:], query_emb[b,:])
// grid = (S/128, B), block = 256 (4 waves). Each wave handles 2 rows/iter:
// lanes 0..31 cover row s (float4 each = 512B), lanes 32..63 cover row s+1,
// so one wave-instruction reads a contiguous aligned 1 KiB. Query chunk lives
// in registers (one float4 per lane). Shuffle-reduce within 32-lane halves.
// ---------------------------------------------------------------------------
__global__ __launch_bounds__(256) void scores_kernel(
    const float* __restrict__ doc_emb,
    const float* __restrict__ query_emb,
    float* __restrict__ scores) {
  const int b     = blockIdx.y;
  const int chunk = blockIdx.x;        // 32 chunks of 128 rows each
  const int tid   = threadIdx.x;       // 0..255
  const int wave  = tid >> 6;          // 0..3
  const int lane  = tid & 63;
  const int half  = lane >> 5;         // 0 or 1
  const int sub   = lane & 31;         // 0..31

  // per-lane query chunk (rows of a batch all use the same query vector)
  const float4 q = ((const float4*)(query_emb + b * EE))[sub];

  const float* base = doc_emb + (size_t)b * SS * EE;
  const int s0 = chunk * 128 + wave * 2 + half;

#pragma unroll
  for (int it = 0; it < 16; ++it) {
    const int s = s0 + it * 8;  // 4 waves * 2 rows = 8 rows per iteration
    const float4 d = ((const float4*)(base + (size_t)s * EE))[sub];
    float p = d.x * q.x + d.y * q.y + d.z * q.z + d.w * q.w;
    // reduce across the 32 lanes of this half-wave
#pragma unroll
    for (int off = 16; off; off >>= 1) p += __shfl_down(p, off, 32);
    if (sub == 0) scores[b * SS + s] = p;
  }
}

// ---------------------------------------------------------------------------
// Kernel 2: per-batch masked softmax + entity segment-sum + log.
// One 1024-thread block per batch (64 blocks).
// ---------------------------------------------------------------------------
__global__ __launch_bounds__(1024) void finish_kernel(
    const float* __restrict__ scores,
    const int* __restrict__ doc_ids,
    const int* __restrict__ seq_length,
    float* __restrict__ out) {
  const int b   = blockIdx.x;
  const int tid = threadIdx.x;  // 0..1023
  const int lane = tid & 63;
  const int wv   = tid >> 6;    // 0..15

  int len = seq_length[b];
  if (len < 1) len = 1;

  __shared__ float red[16];
  __shared__ float s_max, s_sum;
  __shared__ float bins[NENT];

  const float* sc = scores + b * SS;

  // ---- pass 1: masked max ----
  float vals[4];
  float lmax = -1e30f;
#pragma unroll
  for (int i = 0; i < 4; ++i) {
    const int s = tid + i * 1024;
    const float v = (s < len) ? sc[s] : -1e30f;
    vals[i] = v;
    lmax = fmaxf(lmax, v);
  }
#pragma unroll
  for (int off = 32; off; off >>= 1) lmax = fmaxf(lmax, __shfl_down(lmax, off, 64));
  if (lane == 0) red[wv] = lmax;
  __syncthreads();
  if (tid < 16) {
    float m = red[tid];
#pragma unroll
    for (int off = 8; off; off >>= 1) m = fmaxf(m, __shfl_down(m, off, 16));
    if (tid == 0) s_max = m;
  }
  __syncthreads();
  const float mx = s_max;
  __syncthreads();  // red[] about to be reused

  // ---- pass 2: exp + sum ----
  float lsum = 0.f;
#pragma unroll
  for (int i = 0; i < 4; ++i) {
    const int s = tid + i * 1024;
    const float e = (s < len) ? expf(vals[i] - mx) : 0.f;
    vals[i] = e;
    lsum += e;
  }
#pragma unroll
  for (int off = 32; off; off >>= 1) lsum += __shfl_down(lsum, off, 64);
  if (lane == 0) red[wv] = lsum;
  __syncthreads();
  if (tid < 16) {
    float m = red[tid];
#pragma unroll
    for (int off = 8; off; off >>= 1) m += __shfl_down(m, off, 16);
    if (tid == 0) s_sum = m;
  }
  // zero entity bins while the sum reduction settles
  for (int i = tid; i < NENT; i += 1024) bins[i] = 0.f;
  __syncthreads();
  const float inv = 1.f / s_sum;

  // ---- segment-sum into LDS bins ----
  const int* ids = doc_ids + b * SS;
#pragma unroll
  for (int i = 0; i < 4; ++i) {
    const int s = tid + i * 1024;
    if (s < len) atomicAdd(&bins[ids[s]], vals[i] * inv);
  }
  __syncthreads();

  // ---- epilogue: log(sums[0:512] + eps) ----
  if (tid < NOUT) out[b * NOUT + tid] = logf(bins[tid] + 1e-9f);
}

extern "C" void kernel_launch(void* const* d_in, const int* in_sizes, int n_in,
                              void* d_out, int out_size, void* d_ws, size_t ws_size,
                              hipStream_t stream) {
  const float* doc_emb    = (const float*)d_in[0];
  const float* query_emb  = (const float*)d_in[1];
  const int*   doc_ids    = (const int*)d_in[2];
  const int*   seq_length = (const int*)d_in[3];
  float* out    = (float*)d_out;
  float* scores = (float*)d_ws;  // B*S floats = 1 MiB

  dim3 grid1(SS / 128, BB);
  scores_kernel<<<grid1, 256, 0, stream>>>(doc_emb, query_emb, scores);
  finish_kernel<<<BB, 1024, 0, stream>>>(scores, doc_ids, seq_length, out);
}